// Round 1
// 1132.088 us; speedup vs baseline: 1.0043x; 1.0043x over previous
//
#include <hip/hip_runtime.h>
#include <hip/hip_bf16.h>
#include <math.h>

#define NUM_EXPERTS 8
#define NTOK 8192
#define CDIM 1024
#define FDIM 4096
#define MAXSLOTS 17408   /* 16384 slots + 8*128 pad */
#define MAXTILES 136     /* 8 XCDs x 17 tiles */
#define TILES_PER_XCD 17

typedef __bf16 bf16x8 __attribute__((ext_vector_type(8)));
typedef float  f32x4  __attribute__((ext_vector_type(4)));

#define GPTR(p) ((const __attribute__((address_space(1))) unsigned int*)(p))
#define LPTR(p) ((__attribute__((address_space(3))) unsigned int*)(p))

__device__ __forceinline__ float gelu_exact(float v){
  return 0.5f * v * (1.0f + erff(v * 0.70710678118654752f));
}
__device__ __forceinline__ float bf2f(unsigned short u){
  union { unsigned int i; float f; } cv; cv.i = ((unsigned int)u) << 16; return cv.f;
}

// ---------------- router: logits -> top2 -> weights + counts ----------------
__global__ __launch_bounds__(256) void moe_router(
    const float* __restrict__ x, const float* __restrict__ gw,
    int2* __restrict__ topi, float2* __restrict__ topw, int* __restrict__ counts)
{
  int token = blockIdx.x * 4 + (threadIdx.x >> 6);
  int lane  = threadIdx.x & 63;
  int e = lane & 7, part = lane >> 3;
  const float* xr = x + (size_t)token * CDIM;
  float s = 0.f;
  int c0 = part * 128;
  for (int c = c0; c < c0 + 128; ++c) s += xr[c] * gw[c * 8 + e];
  s += __shfl_xor(s, 8); s += __shfl_xor(s, 16); s += __shfl_xor(s, 32);
  float m1 = s; int i1 = e;
  for (int off = 1; off < 8; off <<= 1){
    float ov = __shfl_xor(m1, off); int oi = __shfl_xor(i1, off);
    if (ov > m1 || (ov == m1 && oi < i1)){ m1 = ov; i1 = oi; }
  }
  float l2 = (e == i1) ? -INFINITY : s;
  float m2 = l2; int i2 = e;
  for (int off = 1; off < 8; off <<= 1){
    float ov = __shfl_xor(m2, off); int oi = __shfl_xor(i2, off);
    if (ov > m2 || (ov == m2 && oi < i2)){ m2 = ov; i2 = oi; }
  }
  if (lane == 0){
    float r = expf(m2 - m1);          // p2/p1
    float wa = 1.f / (1.f + r);
    topi[token] = make_int2(i1, i2);
    topw[token] = make_float2(wa, 1.f - wa);
    atomicAdd(&counts[i1], 1);
    atomicAdd(&counts[i2], 1);
  }
}

// ---------------- x fp32 -> bf16 ----------------
__global__ __launch_bounds__(256) void convert_x_kernel(
    const float* __restrict__ x, __hip_bfloat16* __restrict__ xb)
{
  int i = (blockIdx.x * 256 + threadIdx.x) * 4;
  float4 v = *(const float4*)(x + i);
  union { __hip_bfloat16 hh[4]; ushort4 u; } cv;
  cv.hh[0] = __float2bfloat16(v.x);
  cv.hh[1] = __float2bfloat16(v.y);
  cv.hh[2] = __float2bfloat16(v.z);
  cv.hh[3] = __float2bfloat16(v.w);
  *(ushort4*)(xb + i) = cv.u;
}

// ---------------- weight transpose+convert: [z][R][Cc] fp32 -> [z][Cc][R] bf16 ----
__global__ __launch_bounds__(256) void transpose_bf16_kernel(
    const float* __restrict__ in, __hip_bfloat16* __restrict__ outp, int R, int Cc)
{
  __shared__ __hip_bfloat16 tile[64 * 66];
  const size_t msz = (size_t)R * Cc;
  const float* inm = in + (size_t)blockIdx.z * msz;
  __hip_bfloat16* outm = outp + (size_t)blockIdx.z * msz;
  int r0 = blockIdx.y * 64, c0 = blockIdx.x * 64;
  int t = threadIdx.x;
  int r = t & 63, cseg = (t >> 6) * 16;
  const float* src = inm + (size_t)(r0 + r) * Cc + c0 + cseg;
  float4 v0 = ((const float4*)src)[0];
  float4 v1 = ((const float4*)src)[1];
  float4 v2 = ((const float4*)src)[2];
  float4 v3 = ((const float4*)src)[3];
  float vv[16] = {v0.x,v0.y,v0.z,v0.w, v1.x,v1.y,v1.z,v1.w,
                  v2.x,v2.y,v2.z,v2.w, v3.x,v3.y,v3.z,v3.w};
#pragma unroll
  for (int k = 0; k < 16; ++k)
    tile[(cseg + k) * 66 + r] = __float2bfloat16(vv[k]);
  __syncthreads();
#pragma unroll
  for (int p = 0; p < 2; ++p){
    int cc = p * 32 + (t >> 3), ch = (t & 7) * 8;
    const unsigned short* rowp = (const unsigned short*)tile + cc * 66 + ch;
    unsigned int a = *(const unsigned int*)(rowp + 0);
    unsigned int b = *(const unsigned int*)(rowp + 2);
    unsigned int c = *(const unsigned int*)(rowp + 4);
    unsigned int d = *(const unsigned int*)(rowp + 6);
    *(uint4*)(outm + (size_t)(c0 + cc) * R + r0 + ch) = make_uint4(a, b, c, d);
  }
}

// ---------------- scan: expert offsets (128-aligned), tile table, pad fill ----------------
__global__ void scan_kernel(const int* __restrict__ counts, int* cursors, int* num_tiles,
    int* tile_expert, int* tile_slotbase, int* slot_token, float* slot_weight)
{
  int t = threadIdx.x;
  if (t == 0){
    int base = 0, T = 0;
    for (int e = 0; e < NUM_EXPERTS; ++e){
      cursors[e] = base;
      int nt = (counts[e] + 127) >> 7;
      for (int i = 0; i < nt; ++i){ tile_expert[T] = e; tile_slotbase[T] = base + i * 128; ++T; }
      base += nt << 7;
    }
    *num_tiles = T;
  }
  for (int i = t; i < MAXSLOTS; i += 256){ slot_token[i] = 0; slot_weight[i] = 0.f; }
}

// ---------------- assign (token,k) -> slot; record token -> slots ----------------
__global__ void assign_kernel(const int2* __restrict__ topi, const float2* __restrict__ topw,
    int* cursors, int* slot_token, float* slot_weight, int2* __restrict__ token_slots)
{
  int token = blockIdx.x * 256 + threadIdx.x;
  int2 ii = topi[token];
  float2 ww = topw[token];
  int p0 = atomicAdd(&cursors[ii.x], 1);
  slot_token[p0] = token; slot_weight[p0] = ww.x;
  int p1 = atomicAdd(&cursors[ii.y], 1);
  slot_token[p1] = token; slot_weight[p1] = ww.y;
  token_slots[token] = make_int2(p0, p1);
}

// ---------------- pipelined GEMM: Out[tile rows 128][n0..n0+256) ----------------
// 3-deep LDS ring, counted vmcnt (T4), setprio around MFMA (T5), fragment-order
// LDS layout via pre-permuted global sources (zero bank conflicts), swapped-MFMA
// epilogue with direct in-register stores (GELU fused for G1).
template<int KD, int ND, bool G1>
__global__ __launch_bounds__(512, 4) void moe_gemm(
    const __hip_bfloat16* __restrict__ A, const __hip_bfloat16* __restrict__ Bw,
    __hip_bfloat16* __restrict__ Out,
    const int* __restrict__ num_tiles, const int* __restrict__ tile_expert,
    const int* __restrict__ tile_slotbase, const int* __restrict__ slot_token)
{
  constexpr int NT = KD / 32;          // K-tiles of BK=32
  constexpr int NBLK = ND / 256;       // N-panels of 256
  __shared__ __align__(16) char smem[73728];   // A ring 3x8KB | B ring 3x16KB
  const int L = blockIdx.x;
  const int xcd = L & 7;
  const int jdec = L >> 3;
  const int tl = jdec / NBLK;
  const int nb = jdec % NBLK;
  const int tm = xcd * TILES_PER_XCD + tl;
  if (tm >= *num_tiles) return;
  const int e = tile_expert[tm];
  const int sbase = tile_slotbase[tm];
  const int n0 = nb * 256;
  const int t = threadIdx.x;
  const int lane = t & 63, wid = t >> 6;
  const int wm = wid >> 2, wn = wid & 3;      // 2 x 4 wave grid
  const int lr = lane & 15, lq = lane >> 4;

  // per-lane global stage sources (fragment-order permutation baked in)
  const int arowi = sbase + wid * 16 + lr;
  const int arow = G1 ? slot_token[arowi] : arowi;
  const __hip_bfloat16* srcA  = A  + (size_t)arow * KD + lq * 8;
  const __hip_bfloat16* srcB0 = Bw + ((size_t)e * ND + n0 + wid * 16 + lr) * KD + lq * 8;
  const __hip_bfloat16* srcB1 = srcB0 + (size_t)128 * KD;
  // wave-uniform LDS stage destinations (HW writes lane*16 linearly)
  char* dA  = smem + wid * 1024;               // + slot*8192
  char* dB0 = smem + 24576 + wid * 1024;       // + slot*16384
  char* dB1 = dB0 + 8192;

#define STG_A(kt, ss) __builtin_amdgcn_global_load_lds(GPTR(srcA + (size_t)(kt) * 32), LPTR(dA + (ss) * 8192), 16, 0, 0)
#define STG_B(kt, ss) do{ \
    __builtin_amdgcn_global_load_lds(GPTR(srcB0 + (size_t)(kt) * 32), LPTR(dB0 + (ss) * 16384), 16, 0, 0); \
    __builtin_amdgcn_global_load_lds(GPTR(srcB1 + (size_t)(kt) * 32), LPTR(dB1 + (ss) * 16384), 16, 0, 0); }while(0)

  // prologue: K-tiles 0,1 in flight (6 loads/thread); wait oldest 3 (= K-tile 0)
  STG_A(0, 0); STG_B(0, 0);
  STG_A(1, 1); STG_B(1, 1);

  f32x4 acc[4][4] = {};
  const char* rdA = smem + (wm * 4) * 1024 + lane * 16;           // + slot*8192  + i*1024
  const char* rdB = smem + 24576 + (wn * 4) * 1024 + lane * 16;   // + slot*16384 + j*1024

  asm volatile("s_waitcnt vmcnt(3)\n\ts_barrier" ::: "memory");
  __builtin_amdgcn_sched_barrier(0);

  int s = 0;
  for (int kt = 0; kt < NT; ++kt){
    int s2 = s + 2; if (s2 >= 3) s2 -= 3;     // stage target = (kt+2)%3, never the read slot
    const char* pA = rdA + s * 8192;
    const char* pB = rdB + s * 16384;
    bf16x8 b0 = *(const bf16x8*)(pB);
    bf16x8 b1 = *(const bf16x8*)(pB + 1024);
    bf16x8 b2 = *(const bf16x8*)(pB + 2048);
    bf16x8 b3 = *(const bf16x8*)(pB + 3072);
    bf16x8 a0 = *(const bf16x8*)(pA);
    bf16x8 a1 = *(const bf16x8*)(pA + 1024);
    if (kt + 2 < NT) STG_A(kt + 2, s2);
    __builtin_amdgcn_s_setprio(1);
    acc[0][0] = __builtin_amdgcn_mfma_f32_16x16x32_bf16(b0, a0, acc[0][0], 0, 0, 0);
    acc[0][1] = __builtin_amdgcn_mfma_f32_16x16x32_bf16(b1, a0, acc[0][1], 0, 0, 0);
    acc[0][2] = __builtin_amdgcn_mfma_f32_16x16x32_bf16(b2, a0, acc[0][2], 0, 0, 0);
    acc[0][3] = __builtin_amdgcn_mfma_f32_16x16x32_bf16(b3, a0, acc[0][3], 0, 0, 0);
    acc[1][0] = __builtin_amdgcn_mfma_f32_16x16x32_bf16(b0, a1, acc[1][0], 0, 0, 0);
    acc[1][1] = __builtin_amdgcn_mfma_f32_16x16x32_bf16(b1, a1, acc[1][1], 0, 0, 0);
    acc[1][2] = __builtin_amdgcn_mfma_f32_16x16x32_bf16(b2, a1, acc[1][2], 0, 0, 0);
    acc[1][3] = __builtin_amdgcn_mfma_f32_16x16x32_bf16(b3, a1, acc[1][3], 0, 0, 0);
    __builtin_amdgcn_s_setprio(0);
    a0 = *(const bf16x8*)(pA + 2048);
    a1 = *(const bf16x8*)(pA + 3072);
    if (kt + 2 < NT) STG_B(kt + 2, s2);
    __builtin_amdgcn_s_setprio(1);
    acc[2][0] = __builtin_amdgcn_mfma_f32_16x16x32_bf16(b0, a0, acc[2][0], 0, 0, 0);
    acc[2][1] = __builtin_amdgcn_mfma_f32_16x16x32_bf16(b1, a0, acc[2][1], 0, 0, 0);
    acc[2][2] = __builtin_amdgcn_mfma_f32_16x16x32_bf16(b2, a0, acc[2][2], 0, 0, 0);
    acc[2][3] = __builtin_amdgcn_mfma_f32_16x16x32_bf16(b3, a0, acc[2][3], 0, 0, 0);
    acc[3][0] = __builtin_amdgcn_mfma_f32_16x16x32_bf16(b0, a1, acc[3][0], 0, 0, 0);
    acc[3][1] = __builtin_amdgcn_mfma_f32_16x16x32_bf16(b1, a1, acc[3][1], 0, 0, 0);
    acc[3][2] = __builtin_amdgcn_mfma_f32_16x16x32_bf16(b2, a1, acc[3][2], 0, 0, 0);
    acc[3][3] = __builtin_amdgcn_mfma_f32_16x16x32_bf16(b3, a1, acc[3][3], 0, 0, 0);
    __builtin_amdgcn_s_setprio(0);
    if (kt < NT - 2){
      // counted wait: next K-tile's 3 loads (issued last iteration) landed;
      // this iteration's 3 prefetches stay in flight across the barrier
      asm volatile("s_waitcnt vmcnt(3)\n\ts_barrier" ::: "memory");
      __builtin_amdgcn_sched_barrier(0);
    } else if (kt < NT - 1){
      asm volatile("s_waitcnt vmcnt(0)\n\ts_barrier" ::: "memory");
      __builtin_amdgcn_sched_barrier(0);
    }
    s = (s == 2) ? 0 : s + 1;
  }
#undef STG_A
#undef STG_B

  // epilogue: swapped-MFMA layout -> lane holds 4 consecutive output cols per row
  const int orow0 = sbase + wm * 64 + lr;
  const int ocol0 = n0 + wn * 64 + lq * 4;
#pragma unroll
  for (int i = 0; i < 4; ++i){
    __hip_bfloat16* orow = Out + (size_t)(orow0 + i * 16) * ND + ocol0;
#pragma unroll
    for (int j2 = 0; j2 < 4; ++j2){
      f32x4 v = acc[i][j2];
      union { __hip_bfloat16 h4[4]; ushort4 u; } cv;
      if (G1){
        cv.h4[0] = __float2bfloat16(gelu_exact(v[0]));
        cv.h4[1] = __float2bfloat16(gelu_exact(v[1]));
        cv.h4[2] = __float2bfloat16(gelu_exact(v[2]));
        cv.h4[3] = __float2bfloat16(gelu_exact(v[3]));
      } else {
        cv.h4[0] = __float2bfloat16(v[0]);
        cv.h4[1] = __float2bfloat16(v[1]);
        cv.h4[2] = __float2bfloat16(v[2]);
        cv.h4[3] = __float2bfloat16(v[3]);
      }
      *(ushort4*)(orow + j2 * 16) = cv.u;
    }
  }
}

// ---------------- combine: out[token] = w0*y[s0] + w1*y[s1] ----------------
__global__ __launch_bounds__(256) void combine_kernel(
    const __hip_bfloat16* __restrict__ y, const int2* __restrict__ token_slots,
    const float* __restrict__ slot_weight, float* __restrict__ out)
{
  int token = blockIdx.x;
  int c = threadIdx.x * 4;
  int2 ss = token_slots[token];
  float w0 = slot_weight[ss.x], w1 = slot_weight[ss.y];
  ushort4 a = *(const ushort4*)((const unsigned short*)y + (size_t)ss.x * CDIM + c);
  ushort4 b = *(const ushort4*)((const unsigned short*)y + (size_t)ss.y * CDIM + c);
  float4 o;
  o.x = w0 * bf2f(a.x) + w1 * bf2f(b.x);
  o.y = w0 * bf2f(a.y) + w1 * bf2f(b.y);
  o.z = w0 * bf2f(a.z) + w1 * bf2f(b.z);
  o.w = w0 * bf2f(a.w) + w1 * bf2f(b.w);
  *(float4*)(out + (size_t)token * CDIM + c) = o;
}

// ---------------- slow-but-correct fallback (ws too small) ----------------
__global__ __launch_bounds__(256) void naive_kernel(
    const float* __restrict__ x, const float* __restrict__ w1, const float* __restrict__ w2,
    const int2* __restrict__ topi, const float2* __restrict__ topw, float* __restrict__ out)
{
  __shared__ float xs[CDIM];
  __shared__ float hs[FDIM];
  int token = blockIdx.x;
  int t = threadIdx.x;
  for (int i = t; i < CDIM; i += 256) xs[i] = x[(size_t)token * CDIM + i];
  float acc[4] = {0.f, 0.f, 0.f, 0.f};
  int2 ei = topi[token]; float2 ew = topw[token];
  int elist[2] = {ei.x, ei.y}; float wlist[2] = {ew.x, ew.y};
  for (int kk = 0; kk < 2; ++kk){
    int e = elist[kk]; float wgt = wlist[kk];
    __syncthreads();
    for (int f = t; f < FDIM; f += 256){
      const float* wcol = w1 + (size_t)e * CDIM * FDIM + f;
      float s = 0.f;
      for (int c = 0; c < CDIM; ++c) s += xs[c] * wcol[(size_t)c * FDIM];
      hs[f] = gelu_exact(s);
    }
    __syncthreads();
    for (int ii = 0; ii < 4; ++ii){
      int c = ii * 256 + t;
      const float* w2col = w2 + (size_t)e * FDIM * CDIM + c;
      float s = 0.f;
      for (int f = 0; f < FDIM; ++f) s += hs[f] * w2col[(size_t)f * CDIM];
      acc[ii] += wgt * s;
    }
  }
  for (int ii = 0; ii < 4; ++ii) out[(size_t)token * CDIM + ii * 256 + t] = acc[ii];
}

extern "C" void kernel_launch(void* const* d_in, const int* in_sizes, int n_in,
                              void* d_out, int out_size, void* d_ws, size_t ws_size,
                              hipStream_t stream)
{
  const float* x  = (const float*)d_in[0];
  const float* gw = (const float*)d_in[1];
  const float* w1 = (const float*)d_in[2];
  const float* w2 = (const float*)d_in[3];
  float* out = (float*)d_out;
  char* ws = (char*)d_ws;

  int*    counts        = (int*)(ws + 0);
  int*    cursors       = (int*)(ws + 32);
  int*    num_tiles     = (int*)(ws + 64);
  int*    tile_expert   = (int*)(ws + 256);
  int*    tile_slotbase = (int*)(ws + 1024);
  int2*   topi          = (int2*)(ws + 4096);
  float2* topw          = (float2*)(ws + 69632);
  int*    slot_token    = (int*)(ws + 135168);
  float*  slot_weight   = (float*)(ws + 204800);
  int2*   token_slots   = (int2*)(ws + 278528);
  const size_t XBF_OFF = 1u << 20;
  const size_t W1T_OFF = XBF_OFF + (size_t)NTOK * CDIM * 2;
  const size_t W2T_OFF = W1T_OFF + (size_t)NUM_EXPERTS * CDIM * FDIM * 2;
  const size_t H_OFF   = W2T_OFF + (size_t)NUM_EXPERTS * CDIM * FDIM * 2;
  const size_t NEED    = H_OFF + (size_t)MAXSLOTS * FDIM * 2;                  // ~295 MB
  __hip_bfloat16* xbf = (__hip_bfloat16*)(ws + XBF_OFF);
  __hip_bfloat16* w1t = (__hip_bfloat16*)(ws + W1T_OFF);
  __hip_bfloat16* w2t = (__hip_bfloat16*)(ws + W2T_OFF);
  __hip_bfloat16* h   = (__hip_bfloat16*)(ws + H_OFF);
  __hip_bfloat16* y   = (__hip_bfloat16*)(ws + W1T_OFF);  // overlays w1t (dead after gemm1)

  hipMemsetAsync(ws, 0, 4096, stream);

  moe_router<<<NTOK / 4, 256, 0, stream>>>(x, gw, topi, topw, counts);

  if (ws_size >= NEED){
    convert_x_kernel<<<NTOK * CDIM / (4 * 256), 256, 0, stream>>>(x, xbf);
    transpose_bf16_kernel<<<dim3(FDIM / 64, CDIM / 64, NUM_EXPERTS), 256, 0, stream>>>(w1, w1t, CDIM, FDIM);
    transpose_bf16_kernel<<<dim3(CDIM / 64, FDIM / 64, NUM_EXPERTS), 256, 0, stream>>>(w2, w2t, FDIM, CDIM);
    scan_kernel<<<1, 256, 0, stream>>>(counts, cursors, num_tiles, tile_expert, tile_slotbase, slot_token, slot_weight);
    assign_kernel<<<NTOK / 256, 256, 0, stream>>>(topi, topw, cursors, slot_token, slot_weight, token_slots);
    moe_gemm<CDIM, FDIM, true ><<<8 * TILES_PER_XCD * (FDIM / 256), 512, 0, stream>>>(
        xbf, w1t, h, num_tiles, tile_expert, tile_slotbase, slot_token);
    moe_gemm<FDIM, CDIM, false><<<8 * TILES_PER_XCD * (CDIM / 256), 512, 0, stream>>>(
        h, w2t, y, num_tiles, tile_expert, tile_slotbase, slot_token);
    combine_kernel<<<NTOK, 256, 0, stream>>>(y, token_slots, slot_weight, out);
  } else {
    naive_kernel<<<NTOK, 256, 0, stream>>>(x, w1, w2, topi, topw, out);
  }
}

// Round 2
// 994.951 us; speedup vs baseline: 1.1428x; 1.1378x over previous
//
#include <hip/hip_runtime.h>
#include <hip/hip_bf16.h>
#include <math.h>

#define NUM_EXPERTS 8
#define NTOK 8192
#define CDIM 1024
#define FDIM 4096
#define MAXSLOTS 17408   /* 16384 slots + 8*128 pad */
#define MAXTILES 136     /* 8 XCDs x 17 tiles */
#define TILES_PER_XCD 17

typedef __bf16 bf16x8 __attribute__((ext_vector_type(8)));
typedef float  f32x4  __attribute__((ext_vector_type(4)));

#define GPTR(p) ((const __attribute__((address_space(1))) unsigned int*)(p))
#define LPTR(p) ((__attribute__((address_space(3))) unsigned int*)(p))

__device__ __forceinline__ float gelu_exact(float v){
  return 0.5f * v * (1.0f + erff(v * 0.70710678118654752f));
}
__device__ __forceinline__ float bf2f(unsigned short u){
  union { unsigned int i; float f; } cv; cv.i = ((unsigned int)u) << 16; return cv.f;
}

// ---------------- router: logits -> top2 -> weights + counts ----------------
__global__ __launch_bounds__(256) void moe_router(
    const float* __restrict__ x, const float* __restrict__ gw,
    int2* __restrict__ topi, float2* __restrict__ topw, int* __restrict__ counts)
{
  int token = blockIdx.x * 4 + (threadIdx.x >> 6);
  int lane  = threadIdx.x & 63;
  int e = lane & 7, part = lane >> 3;
  const float* xr = x + (size_t)token * CDIM;
  float s = 0.f;
  int c0 = part * 128;
  for (int c = c0; c < c0 + 128; ++c) s += xr[c] * gw[c * 8 + e];
  s += __shfl_xor(s, 8); s += __shfl_xor(s, 16); s += __shfl_xor(s, 32);
  float m1 = s; int i1 = e;
  for (int off = 1; off < 8; off <<= 1){
    float ov = __shfl_xor(m1, off); int oi = __shfl_xor(i1, off);
    if (ov > m1 || (ov == m1 && oi < i1)){ m1 = ov; i1 = oi; }
  }
  float l2 = (e == i1) ? -INFINITY : s;
  float m2 = l2; int i2 = e;
  for (int off = 1; off < 8; off <<= 1){
    float ov = __shfl_xor(m2, off); int oi = __shfl_xor(i2, off);
    if (ov > m2 || (ov == m2 && oi < i2)){ m2 = ov; i2 = oi; }
  }
  if (lane == 0){
    float r = expf(m2 - m1);          // p2/p1
    float wa = 1.f / (1.f + r);
    topi[token] = make_int2(i1, i2);
    topw[token] = make_float2(wa, 1.f - wa);
    atomicAdd(&counts[i1], 1);
    atomicAdd(&counts[i2], 1);
  }
}

// ---------------- x fp32 -> bf16 ----------------
__global__ __launch_bounds__(256) void convert_x_kernel(
    const float* __restrict__ x, __hip_bfloat16* __restrict__ xb)
{
  int i = (blockIdx.x * 256 + threadIdx.x) * 4;
  float4 v = *(const float4*)(x + i);
  union { __hip_bfloat16 hh[4]; ushort4 u; } cv;
  cv.hh[0] = __float2bfloat16(v.x);
  cv.hh[1] = __float2bfloat16(v.y);
  cv.hh[2] = __float2bfloat16(v.z);
  cv.hh[3] = __float2bfloat16(v.w);
  *(ushort4*)(xb + i) = cv.u;
}

// ---------------- weight transpose+convert: [z][R][Cc] fp32 -> [z][Cc][R] bf16 ----
__global__ __launch_bounds__(256) void transpose_bf16_kernel(
    const float* __restrict__ in, __hip_bfloat16* __restrict__ outp, int R, int Cc)
{
  __shared__ __hip_bfloat16 tile[64 * 66];
  const size_t msz = (size_t)R * Cc;
  const float* inm = in + (size_t)blockIdx.z * msz;
  __hip_bfloat16* outm = outp + (size_t)blockIdx.z * msz;
  int r0 = blockIdx.y * 64, c0 = blockIdx.x * 64;
  int t = threadIdx.x;
  int r = t & 63, cseg = (t >> 6) * 16;
  const float* src = inm + (size_t)(r0 + r) * Cc + c0 + cseg;
  float4 v0 = ((const float4*)src)[0];
  float4 v1 = ((const float4*)src)[1];
  float4 v2 = ((const float4*)src)[2];
  float4 v3 = ((const float4*)src)[3];
  float vv[16] = {v0.x,v0.y,v0.z,v0.w, v1.x,v1.y,v1.z,v1.w,
                  v2.x,v2.y,v2.z,v2.w, v3.x,v3.y,v3.z,v3.w};
#pragma unroll
  for (int k = 0; k < 16; ++k)
    tile[(cseg + k) * 66 + r] = __float2bfloat16(vv[k]);
  __syncthreads();
#pragma unroll
  for (int p = 0; p < 2; ++p){
    int cc = p * 32 + (t >> 3), ch = (t & 7) * 8;
    const unsigned short* rowp = (const unsigned short*)tile + cc * 66 + ch;
    unsigned int a = *(const unsigned int*)(rowp + 0);
    unsigned int b = *(const unsigned int*)(rowp + 2);
    unsigned int c = *(const unsigned int*)(rowp + 4);
    unsigned int d = *(const unsigned int*)(rowp + 6);
    *(uint4*)(outm + (size_t)(c0 + cc) * R + r0 + ch) = make_uint4(a, b, c, d);
  }
}

// ---------------- scan: expert offsets (128-aligned), tile table, pad fill ----------------
__global__ void scan_kernel(const int* __restrict__ counts, int* cursors, int* num_tiles,
    int* tile_expert, int* tile_slotbase, int* slot_token, float* slot_weight)
{
  int t = threadIdx.x;
  if (t == 0){
    int base = 0, T = 0;
    for (int e = 0; e < NUM_EXPERTS; ++e){
      cursors[e] = base;
      int nt = (counts[e] + 127) >> 7;
      for (int i = 0; i < nt; ++i){ tile_expert[T] = e; tile_slotbase[T] = base + i * 128; ++T; }
      base += nt << 7;
    }
    *num_tiles = T;
  }
  for (int i = t; i < MAXSLOTS; i += 256){ slot_token[i] = 0; slot_weight[i] = 0.f; }
}

// ---------------- assign (token,k) -> slot; record token -> slots ----------------
__global__ void assign_kernel(const int2* __restrict__ topi, const float2* __restrict__ topw,
    int* cursors, int* slot_token, float* slot_weight, int2* __restrict__ token_slots)
{
  int token = blockIdx.x * 256 + threadIdx.x;
  int2 ii = topi[token];
  float2 ww = topw[token];
  int p0 = atomicAdd(&cursors[ii.x], 1);
  slot_token[p0] = token; slot_weight[p0] = ww.x;
  int p1 = atomicAdd(&cursors[ii.y], 1);
  slot_token[p1] = token; slot_weight[p1] = ww.y;
  token_slots[token] = make_int2(p0, p1);
}

// ---------------- pipelined GEMM: Out[tile rows 128][n0..n0+256) ----------------
// BK=64, ring-3 LDS (144KB), 128B-coalesced global_load_lds staging with XOR
// bank-swizzle baked into the per-lane global source (rule #21: swizzle on
// source AND read, linear LDS dest). Counted vmcnt(6) (T4), setprio (T5),
// swapped-MFMA direct-store epilogue (GELU fused for G1).
template<int KD, int ND, bool G1>
__global__ __launch_bounds__(512, 2) void moe_gemm(
    const __hip_bfloat16* __restrict__ A, const __hip_bfloat16* __restrict__ Bw,
    __hip_bfloat16* __restrict__ Out,
    const int* __restrict__ num_tiles, const int* __restrict__ tile_expert,
    const int* __restrict__ tile_slotbase, const int* __restrict__ slot_token)
{
  constexpr int NT = KD / 64;          // K-tiles of BK=64
  constexpr int NBLK = ND / 256;       // N-panels of 256
  __shared__ __align__(16) char smem[147456];   // A ring 3x16KB | B ring 3x32KB
  const int L = blockIdx.x;
  const int xcd = L & 7;
  const int jdec = L >> 3;
  const int tl = jdec / NBLK;
  const int nb = jdec % NBLK;
  const int tm = xcd * TILES_PER_XCD + tl;
  if (tm >= *num_tiles) return;
  const int e = tile_expert[tm];
  const int sbase = tile_slotbase[tm];
  const int n0 = nb * 256;
  const int t = threadIdx.x;
  const int lane = t & 63, wid = t >> 6;
  const int wm = wid >> 2, wn = wid & 3;      // 2 x 4 wave grid
  const int lr = lane & 15, lq = lane >> 4;

  // ---- staging geometry: lane l -> dest row (l>>3), dest chunk (l&7);
  // global chunk pre-swizzled so LDS[r][c] holds global chunk c^(r&7).
  const int srow = lane >> 3;                 // 0..7
  const int sch  = (lane & 7) ^ srow;         // swizzled 16B-chunk index
  const __hip_bfloat16* sA[2];
  const __hip_bfloat16* sB4[4];
#pragma unroll
  for (int hh = 0; hh < 2; ++hh){
    int rA = (wid + 8 * hh) * 8 + srow;                       // 0..127
    int grow = G1 ? slot_token[sbase + rA] : (sbase + rA);
    sA[hh] = A + (size_t)grow * KD + sch * 8;
  }
#pragma unroll
  for (int hh = 0; hh < 4; ++hh){
    int rB = (wid + 8 * hh) * 8 + srow;                       // 0..255
    sB4[hh] = Bw + ((size_t)e * ND + n0 + rB) * KD + sch * 8;
  }
  // wave-uniform LDS stage bases (HW adds lane*16 linearly)
  char* dA0 = smem + wid * 1024;               // + hh*8192 + ss*16384
  char* dB0 = smem + 49152 + wid * 1024;       // + hh*8192 + ss*32768

#define STAGE_A(ss) do{ \
    __builtin_amdgcn_global_load_lds(GPTR(sA[0]), LPTR(dA0 + (ss) * 16384 + 0 * 8192), 16, 0, 0); \
    __builtin_amdgcn_global_load_lds(GPTR(sA[1]), LPTR(dA0 + (ss) * 16384 + 1 * 8192), 16, 0, 0); }while(0)
#define STAGE_B(ss) do{ \
    __builtin_amdgcn_global_load_lds(GPTR(sB4[0]), LPTR(dB0 + (ss) * 32768 + 0 * 8192), 16, 0, 0); \
    __builtin_amdgcn_global_load_lds(GPTR(sB4[1]), LPTR(dB0 + (ss) * 32768 + 1 * 8192), 16, 0, 0); \
    __builtin_amdgcn_global_load_lds(GPTR(sB4[2]), LPTR(dB0 + (ss) * 32768 + 2 * 8192), 16, 0, 0); \
    __builtin_amdgcn_global_load_lds(GPTR(sB4[3]), LPTR(dB0 + (ss) * 32768 + 3 * 8192), 16, 0, 0); }while(0)
#define ADV() do{ sA[0]+=64; sA[1]+=64; sB4[0]+=64; sB4[1]+=64; sB4[2]+=64; sB4[3]+=64; }while(0)

  // prologue: K-tiles 0,1 in flight (12 loads/thread); wait oldest 6 (= tile 0)
  STAGE_A(0); STAGE_B(0); ADV();
  STAGE_A(1); STAGE_B(1); ADV();

  f32x4 acc[4][4] = {};
  // read bases: row-major [row][128B], chunk swizzled by row&7
  const char* rdA = smem + (wm * 64 + lr) * 128;             // + s*16384 + rb*2048 + swz
  const char* rdB = smem + 49152 + (wn * 64 + lr) * 128;     // + s*32768 + cb*2048 + swz
  const int x7 = lr & 7;
  const int swz0 = ((0 | lq) ^ x7) * 16;     // k-chunks 0..3  (kk=0)
  const int swz1 = ((4 | lq) ^ x7) * 16;     // k-chunks 4..7  (kk=1)

  asm volatile("s_waitcnt vmcnt(6)\n\ts_barrier" ::: "memory");
  __builtin_amdgcn_sched_barrier(0);

  int s = 0;
  for (int kt = 0; kt < NT; ++kt){
    int s2 = s + 2; if (s2 >= 3) s2 -= 3;     // stage target, never the read slot
    const char* pA = rdA + s * 16384;
    const char* pB = rdB + s * 32768;
    bf16x8 a0 = *(const bf16x8*)(pA + 0 * 2048 + swz0);
    bf16x8 a1 = *(const bf16x8*)(pA + 1 * 2048 + swz0);
    bf16x8 a2 = *(const bf16x8*)(pA + 2 * 2048 + swz0);
    bf16x8 a3 = *(const bf16x8*)(pA + 3 * 2048 + swz0);
    bf16x8 b0 = *(const bf16x8*)(pB + 0 * 2048 + swz0);
    bf16x8 b1 = *(const bf16x8*)(pB + 1 * 2048 + swz0);
    bf16x8 b2 = *(const bf16x8*)(pB + 2 * 2048 + swz0);
    bf16x8 b3 = *(const bf16x8*)(pB + 3 * 2048 + swz0);
    const bool pf = (kt + 2 < NT);
    if (pf) STAGE_A(s2);
    __builtin_amdgcn_s_setprio(1);
    acc[0][0] = __builtin_amdgcn_mfma_f32_16x16x32_bf16(b0, a0, acc[0][0], 0, 0, 0);
    acc[0][1] = __builtin_amdgcn_mfma_f32_16x16x32_bf16(b1, a0, acc[0][1], 0, 0, 0);
    acc[0][2] = __builtin_amdgcn_mfma_f32_16x16x32_bf16(b2, a0, acc[0][2], 0, 0, 0);
    acc[0][3] = __builtin_amdgcn_mfma_f32_16x16x32_bf16(b3, a0, acc[0][3], 0, 0, 0);
    acc[1][0] = __builtin_amdgcn_mfma_f32_16x16x32_bf16(b0, a1, acc[1][0], 0, 0, 0);
    acc[1][1] = __builtin_amdgcn_mfma_f32_16x16x32_bf16(b1, a1, acc[1][1], 0, 0, 0);
    acc[1][2] = __builtin_amdgcn_mfma_f32_16x16x32_bf16(b2, a1, acc[1][2], 0, 0, 0);
    acc[1][3] = __builtin_amdgcn_mfma_f32_16x16x32_bf16(b3, a1, acc[1][3], 0, 0, 0);
    acc[2][0] = __builtin_amdgcn_mfma_f32_16x16x32_bf16(b0, a2, acc[2][0], 0, 0, 0);
    acc[2][1] = __builtin_amdgcn_mfma_f32_16x16x32_bf16(b1, a2, acc[2][1], 0, 0, 0);
    acc[2][2] = __builtin_amdgcn_mfma_f32_16x16x32_bf16(b2, a2, acc[2][2], 0, 0, 0);
    acc[2][3] = __builtin_amdgcn_mfma_f32_16x16x32_bf16(b3, a2, acc[2][3], 0, 0, 0);
    acc[3][0] = __builtin_amdgcn_mfma_f32_16x16x32_bf16(b0, a3, acc[3][0], 0, 0, 0);
    acc[3][1] = __builtin_amdgcn_mfma_f32_16x16x32_bf16(b1, a3, acc[3][1], 0, 0, 0);
    acc[3][2] = __builtin_amdgcn_mfma_f32_16x16x32_bf16(b2, a3, acc[3][2], 0, 0, 0);
    acc[3][3] = __builtin_amdgcn_mfma_f32_16x16x32_bf16(b3, a3, acc[3][3], 0, 0, 0);
    __builtin_amdgcn_s_setprio(0);
    a0 = *(const bf16x8*)(pA + 0 * 2048 + swz1);
    a1 = *(const bf16x8*)(pA + 1 * 2048 + swz1);
    a2 = *(const bf16x8*)(pA + 2 * 2048 + swz1);
    a3 = *(const bf16x8*)(pA + 3 * 2048 + swz1);
    b0 = *(const bf16x8*)(pB + 0 * 2048 + swz1);
    b1 = *(const bf16x8*)(pB + 1 * 2048 + swz1);
    b2 = *(const bf16x8*)(pB + 2 * 2048 + swz1);
    b3 = *(const bf16x8*)(pB + 3 * 2048 + swz1);
    if (pf){ STAGE_B(s2); ADV(); }
    __builtin_amdgcn_s_setprio(1);
    acc[0][0] = __builtin_amdgcn_mfma_f32_16x16x32_bf16(b0, a0, acc[0][0], 0, 0, 0);
    acc[0][1] = __builtin_amdgcn_mfma_f32_16x16x32_bf16(b1, a0, acc[0][1], 0, 0, 0);
    acc[0][2] = __builtin_amdgcn_mfma_f32_16x16x32_bf16(b2, a0, acc[0][2], 0, 0, 0);
    acc[0][3] = __builtin_amdgcn_mfma_f32_16x16x32_bf16(b3, a0, acc[0][3], 0, 0, 0);
    acc[1][0] = __builtin_amdgcn_mfma_f32_16x16x32_bf16(b0, a1, acc[1][0], 0, 0, 0);
    acc[1][1] = __builtin_amdgcn_mfma_f32_16x16x32_bf16(b1, a1, acc[1][1], 0, 0, 0);
    acc[1][2] = __builtin_amdgcn_mfma_f32_16x16x32_bf16(b2, a1, acc[1][2], 0, 0, 0);
    acc[1][3] = __builtin_amdgcn_mfma_f32_16x16x32_bf16(b3, a1, acc[1][3], 0, 0, 0);
    acc[2][0] = __builtin_amdgcn_mfma_f32_16x16x32_bf16(b0, a2, acc[2][0], 0, 0, 0);
    acc[2][1] = __builtin_amdgcn_mfma_f32_16x16x32_bf16(b1, a2, acc[2][1], 0, 0, 0);
    acc[2][2] = __builtin_amdgcn_mfma_f32_16x16x32_bf16(b2, a2, acc[2][2], 0, 0, 0);
    acc[2][3] = __builtin_amdgcn_mfma_f32_16x16x32_bf16(b3, a2, acc[2][3], 0, 0, 0);
    acc[3][0] = __builtin_amdgcn_mfma_f32_16x16x32_bf16(b0, a3, acc[3][0], 0, 0, 0);
    acc[3][1] = __builtin_amdgcn_mfma_f32_16x16x32_bf16(b1, a3, acc[3][1], 0, 0, 0);
    acc[3][2] = __builtin_amdgcn_mfma_f32_16x16x32_bf16(b2, a3, acc[3][2], 0, 0, 0);
    acc[3][3] = __builtin_amdgcn_mfma_f32_16x16x32_bf16(b3, a3, acc[3][3], 0, 0, 0);
    __builtin_amdgcn_s_setprio(0);
    if (kt < NT - 2){
      // counted wait: K-tile kt+1's 6 loads landed; kt+2's 6 stay in flight
      asm volatile("s_waitcnt vmcnt(6)\n\ts_barrier" ::: "memory");
      __builtin_amdgcn_sched_barrier(0);
    } else if (kt < NT - 1){
      asm volatile("s_waitcnt vmcnt(0)\n\ts_barrier" ::: "memory");
      __builtin_amdgcn_sched_barrier(0);
    }
    s = (s == 2) ? 0 : s + 1;
  }
#undef STAGE_A
#undef STAGE_B
#undef ADV

  // epilogue: swapped-MFMA layout -> lane holds 4 consecutive output cols per row
  const int orow0 = sbase + wm * 64 + lr;
  const int ocol0 = n0 + wn * 64 + lq * 4;
#pragma unroll
  for (int i = 0; i < 4; ++i){
    __hip_bfloat16* orow = Out + (size_t)(orow0 + i * 16) * ND + ocol0;
#pragma unroll
    for (int j2 = 0; j2 < 4; ++j2){
      f32x4 v = acc[i][j2];
      union { __hip_bfloat16 h4[4]; ushort4 u; } cv;
      if (G1){
        cv.h4[0] = __float2bfloat16(gelu_exact(v[0]));
        cv.h4[1] = __float2bfloat16(gelu_exact(v[1]));
        cv.h4[2] = __float2bfloat16(gelu_exact(v[2]));
        cv.h4[3] = __float2bfloat16(gelu_exact(v[3]));
      } else {
        cv.h4[0] = __float2bfloat16(v[0]);
        cv.h4[1] = __float2bfloat16(v[1]);
        cv.h4[2] = __float2bfloat16(v[2]);
        cv.h4[3] = __float2bfloat16(v[3]);
      }
      *(ushort4*)(orow + j2 * 16) = cv.u;
    }
  }
}

// ---------------- combine: out[token] = w0*y[s0] + w1*y[s1] ----------------
__global__ __launch_bounds__(256) void combine_kernel(
    const __hip_bfloat16* __restrict__ y, const int2* __restrict__ token_slots,
    const float* __restrict__ slot_weight, float* __restrict__ out)
{
  int token = blockIdx.x;
  int c = threadIdx.x * 4;
  int2 ss = token_slots[token];
  float w0 = slot_weight[ss.x], w1 = slot_weight[ss.y];
  ushort4 a = *(const ushort4*)((const unsigned short*)y + (size_t)ss.x * CDIM + c);
  ushort4 b = *(const ushort4*)((const unsigned short*)y + (size_t)ss.y * CDIM + c);
  float4 o;
  o.x = w0 * bf2f(a.x) + w1 * bf2f(b.x);
  o.y = w0 * bf2f(a.y) + w1 * bf2f(b.y);
  o.z = w0 * bf2f(a.z) + w1 * bf2f(b.z);
  o.w = w0 * bf2f(a.w) + w1 * bf2f(b.w);
  *(float4*)(out + (size_t)token * CDIM + c) = o;
}

// ---------------- slow-but-correct fallback (ws too small) ----------------
__global__ __launch_bounds__(256) void naive_kernel(
    const float* __restrict__ x, const float* __restrict__ w1, const float* __restrict__ w2,
    const int2* __restrict__ topi, const float2* __restrict__ topw, float* __restrict__ out)
{
  __shared__ float xs[CDIM];
  __shared__ float hs[FDIM];
  int token = blockIdx.x;
  int t = threadIdx.x;
  for (int i = t; i < CDIM; i += 256) xs[i] = x[(size_t)token * CDIM + i];
  float acc[4] = {0.f, 0.f, 0.f, 0.f};
  int2 ei = topi[token]; float2 ew = topw[token];
  int elist[2] = {ei.x, ei.y}; float wlist[2] = {ew.x, ew.y};
  for (int kk = 0; kk < 2; ++kk){
    int e = elist[kk]; float wgt = wlist[kk];
    __syncthreads();
    for (int f = t; f < FDIM; f += 256){
      const float* wcol = w1 + (size_t)e * CDIM * FDIM + f;
      float s = 0.f;
      for (int c = 0; c < CDIM; ++c) s += xs[c] * wcol[(size_t)c * FDIM];
      hs[f] = gelu_exact(s);
    }
    __syncthreads();
    for (int ii = 0; ii < 4; ++ii){
      int c = ii * 256 + t;
      const float* w2col = w2 + (size_t)e * FDIM * CDIM + c;
      float s = 0.f;
      for (int f = 0; f < FDIM; ++f) s += hs[f] * w2col[(size_t)f * CDIM];
      acc[ii] += wgt * s;
    }
  }
  for (int ii = 0; ii < 4; ++ii) out[(size_t)token * CDIM + ii * 256 + t] = acc[ii];
}

extern "C" void kernel_launch(void* const* d_in, const int* in_sizes, int n_in,
                              void* d_out, int out_size, void* d_ws, size_t ws_size,
                              hipStream_t stream)
{
  const float* x  = (const float*)d_in[0];
  const float* gw = (const float*)d_in[1];
  const float* w1 = (const float*)d_in[2];
  const float* w2 = (const float*)d_in[3];
  float* out = (float*)d_out;
  char* ws = (char*)d_ws;

  int*    counts        = (int*)(ws + 0);
  int*    cursors       = (int*)(ws + 32);
  int*    num_tiles     = (int*)(ws + 64);
  int*    tile_expert   = (int*)(ws + 256);
  int*    tile_slotbase = (int*)(ws + 1024);
  int2*   topi          = (int2*)(ws + 4096);
  float2* topw          = (float2*)(ws + 69632);
  int*    slot_token    = (int*)(ws + 135168);
  float*  slot_weight   = (float*)(ws + 204800);
  int2*   token_slots   = (int2*)(ws + 278528);
  const size_t XBF_OFF = 1u << 20;
  const size_t W1T_OFF = XBF_OFF + (size_t)NTOK * CDIM * 2;
  const size_t W2T_OFF = W1T_OFF + (size_t)NUM_EXPERTS * CDIM * FDIM * 2;
  const size_t H_OFF   = W2T_OFF + (size_t)NUM_EXPERTS * CDIM * FDIM * 2;
  const size_t NEED    = H_OFF + (size_t)MAXSLOTS * FDIM * 2;                  // ~295 MB
  __hip_bfloat16* xbf = (__hip_bfloat16*)(ws + XBF_OFF);
  __hip_bfloat16* w1t = (__hip_bfloat16*)(ws + W1T_OFF);
  __hip_bfloat16* w2t = (__hip_bfloat16*)(ws + W2T_OFF);
  __hip_bfloat16* h   = (__hip_bfloat16*)(ws + H_OFF);
  __hip_bfloat16* y   = (__hip_bfloat16*)(ws + W1T_OFF);  // overlays w1t (dead after gemm1)

  hipMemsetAsync(ws, 0, 4096, stream);

  moe_router<<<NTOK / 4, 256, 0, stream>>>(x, gw, topi, topw, counts);

  if (ws_size >= NEED){
    convert_x_kernel<<<NTOK * CDIM / (4 * 256), 256, 0, stream>>>(x, xbf);
    transpose_bf16_kernel<<<dim3(FDIM / 64, CDIM / 64, NUM_EXPERTS), 256, 0, stream>>>(w1, w1t, CDIM, FDIM);
    transpose_bf16_kernel<<<dim3(CDIM / 64, FDIM / 64, NUM_EXPERTS), 256, 0, stream>>>(w2, w2t, FDIM, CDIM);
    scan_kernel<<<1, 256, 0, stream>>>(counts, cursors, num_tiles, tile_expert, tile_slotbase, slot_token, slot_weight);
    assign_kernel<<<NTOK / 256, 256, 0, stream>>>(topi, topw, cursors, slot_token, slot_weight, token_slots);
    moe_gemm<CDIM, FDIM, true ><<<8 * TILES_PER_XCD * (FDIM / 256), 512, 0, stream>>>(
        xbf, w1t, h, num_tiles, tile_expert, tile_slotbase, slot_token);
    moe_gemm<FDIM, CDIM, false><<<8 * TILES_PER_XCD * (CDIM / 256), 512, 0, stream>>>(
        h, w2t, y, num_tiles, tile_expert, tile_slotbase, slot_token);
    combine_kernel<<<NTOK, 256, 0, stream>>>(y, token_slots, slot_weight, out);
  } else {
    naive_kernel<<<NTOK, 256, 0, stream>>>(x, w1, w2, topi, topw, out);
  }
}